// Round 7
// baseline (11766.420 us; speedup 1.0000x reference)
//
#include <hip/hip_runtime.h>
#include <hip/hip_bf16.h>
#include <math.h>

// Problem dims
#define B_   128
#define T_   800
#define H_   512
#define K_   10
#define C_   80
#define U_   64
#define IN_  3

// Decomposition: 4 groups x 32 batches; 64 blocks/group; each block owns 8 units (32 gate rows)
#define NG   4
#define BPG  64
#define BT   32
#define NT   256
#define KROW 608            // LDS padded K extent (592 real + 16 zero)
#define HB   512            // gbuf row width (h only)

// ws layout (4-byte units): gbuf[2][128][512] u32 | pacc[NG][32][30] i64 | flags
#define WS_PACC_F  (2*B_*HB)
#define WS_BAR_F   (WS_PACC_F + NG*BT*30*2)
#define WS_TOTAL_F (WS_BAR_F + NG*8*32)

// out layout (f32 elements): h_seq | w_seq | phi_seq
#define OFF_H    0ull
#define OFF_W    ((size_t)B_ * T_ * H_)
#define OFF_PHI  (OFF_W + (size_t)B_ * T_ * C_)

typedef __attribute__((ext_vector_type(8))) short short8;
typedef __attribute__((ext_vector_type(4))) float f32x4;

// XOR swizzle of 16B units within each 64B span, keyed by row
#define SWZB(row)    (((row) ^ ((row) >> 2)) & 3)
#define SWIDX(row,k) ((row)*KROW + ((((k) >> 3) ^ SWZB(row)) << 3) + ((k) & 7))
#define LDFRAG(arr,row,u) (*(const short8*)&(arr)[(row)*KROW + (((u) ^ SWZB(row)) << 3)])

// ---- sync primitives (rounds 3-5 proven) ----
__device__ __forceinline__ void stb_u32(unsigned* p, unsigned v) {
  asm volatile("global_store_dword %0, %1, off sc0 sc1" :: "v"(p), "v"(v) : "memory");
}
__device__ __forceinline__ void fence_vm() {
  asm volatile("s_waitcnt vmcnt(0)" ::: "memory");
}
__device__ __forceinline__ void flag_add(unsigned* p) {
  __hip_atomic_fetch_add(p, 1u, __ATOMIC_RELAXED, __HIP_MEMORY_SCOPE_AGENT);
}
__device__ __forceinline__ unsigned flag_ld(unsigned* p) {
  return __hip_atomic_load(p, __ATOMIC_RELAXED, __HIP_MEMORY_SCOPE_AGENT);
}
__device__ __forceinline__ void acq_fence(unsigned* p) {
  (void)__hip_atomic_load(p, __ATOMIC_ACQUIRE, __HIP_MEMORY_SCOPE_AGENT);
}
__device__ __forceinline__ float sigmoidf_(float v) { return 1.0f / (1.0f + expf(-v)); }
__device__ __forceinline__ unsigned pack_hl(float v) {
  unsigned hb = __float_as_uint(v) >> 16;
  float rs = v - __uint_as_float(hb << 16);
  unsigned lb = __float_as_uint(rs) >> 16;
  return (hb << 16) | lb;
}
__device__ __forceinline__ float comb_hl(short h, short l) {
  return __uint_as_float((unsigned)(unsigned short)h << 16) +
         __uint_as_float((unsigned)(unsigned short)l << 16);
}

__global__ void __launch_bounds__(256, 2)
init_ws_kernel(float* __restrict__ ws) {
  size_t i = (size_t)blockIdx.x * 256 + threadIdx.x;
  const size_t n = (size_t)WS_TOTAL_F;
  const size_t stride = (size_t)gridDim.x * 256;
  for (; i < n; i += stride) ws[i] = 0.0f;
}

__global__ void __launch_bounds__(NT, 1)
graves_kernel(const float* __restrict__ x,       // [B][T][3]
              const int*   __restrict__ sent,    // [B][U]
              const float* __restrict__ smask,   // [B][U]
              const float* __restrict__ W_ih,    // [2048][83]
              const float* __restrict__ W_hh,    // [2048][512]
              const float* __restrict__ b_ih,    // [2048]
              const float* __restrict__ b_hh,    // [2048]
              const float* __restrict__ W_win,   // [30][512]
              const float* __restrict__ b_win,   // [30]
              float* __restrict__ out,
              float* __restrict__ ws)
{
  const int tid = threadIdx.x;
  const int bid = blockIdx.x;
  const int g   = bid >> 6;
  const int ub  = bid & (BPG - 1);
  const int b0  = g * BT;
  const int u0  = ub * 8;

  unsigned*  gbuf   = (unsigned*)ws;
  long long* pacc_g = (long long*)(ws + WS_PACC_F) + (size_t)g * (BT * 30);
  unsigned*  fb     = (unsigned*)(ws + WS_BAR_F) + (size_t)g * 256;
  unsigned*  c1l    = fb;            // 4 lines x 16 arrivals/step

  // ---- LDS: 162,240 B declared ----
  __shared__ __align__(16) short whi[32 * KROW];   // 38,912 B
  __shared__ __align__(16) short wlo[32 * KROW];   // 38,912 B
  __shared__ __align__(16) short shi[32 * KROW];   // 38,912 B
  __shared__ __align__(16) short slo[32 * KROW];   // 38,912 B
  __shared__ float pbufS[32][32];                  //  4,096 B  p-params / gate-reduce (time-disjoint)
  __shared__ float hT[8 * 32];                     //  1,024 B  own units' exact f32 h
  __shared__ float wwin[8 * 30];                   //    960 B  W_win slice (own units)
  __shared__ float xwb[32 * 4];                    //    512 B
  float* pbf = &pbufS[0][0];

  // ---- one-time staging: gate weights (split bf16, swizzled) ----
  for (int idx = tid; idx < 32 * KROW; idx += NT) {
    const int r = idx / KROW, k = idx - r * KROW;
    const int uu = r >> 2, gate = r & 3, gr = gate * H_ + u0 + uu;
    float wv = 0.0f;
    if (k < H_)           wv = W_hh[(size_t)gr * H_ + k];
    else if (k < H_ + C_) wv = W_ih[(size_t)gr * (IN_ + C_) + IN_ + (k - H_)];
    const unsigned hb = __float_as_uint(wv) >> 16;
    const float rs = wv - __uint_as_float(hb << 16);
    const unsigned lb = __float_as_uint(rs) >> 16;
    const int li = SWIDX(r, k);
    whi[li] = (short)hb;
    wlo[li] = (short)lb;
  }
  for (int idx = tid; idx < 32 * 16; idx += NT) {  // zero state pad cols 592..607
    const int b2 = idx >> 4, k = (H_ + C_) + (idx & 15);
    shi[SWIDX(b2, k)] = 0; slo[SWIDX(b2, k)] = 0;
  }
  if (tid < 32) {
    const int uu = tid >> 2, gate = tid & 3, gr = gate * H_ + u0 + uu;
    xwb[tid * 4 + 0] = W_ih[(size_t)gr * (IN_ + C_) + 0];
    xwb[tid * 4 + 1] = W_ih[(size_t)gr * (IN_ + C_) + 1];
    xwb[tid * 4 + 2] = W_ih[(size_t)gr * (IN_ + C_) + 2];
    xwb[tid * 4 + 3] = b_ih[gr] + b_hh[gr];
  }
  for (int idx = tid; idx < 240; idx += NT) {      // W_win slice (exact f32)
    const int uu = idx / 30, j = idx - uu * 30;
    wwin[idx] = W_win[(size_t)j * H_ + u0 + uu];
  }

  // wave identity
  const int lane = tid & 63;
  const int wid  = tid >> 6;
  const int ni   = wid & 1;          // gate GEMM batch-tile
  const int kh   = wid >> 1;         // gate GEMM k-half
  const int r16  = lane & 15;
  const int g4   = lane >> 4;
  const int bb   = ni * 16 + r16;

  // ---- per-thread sent/mask registers for phi/scatter: thread = (pb, ug) ----
  const int pb = tid >> 3, ug = tid & 7;
  float msk[8]; int snt[8];
  #pragma unroll
  for (int i = 0; i < 8; ++i) {
    msk[i] = smask[(size_t)(b0 + pb) * U_ + ug * 8 + i];
    snt[i] = sent [(size_t)(b0 + pb) * U_ + ug * 8 + i];
  }
  const bool isWriter = (ub < BT);
  const int  wb_b = b0 + ub;
  __syncthreads();

  float cr0 = 0.0f, cr1 = 0.0f;        // c-state (kh==0 lanes)
  long long prevp[4] = {0, 0, 0, 0};   // published fixed-point p-partials (per item)
  float kprevf[4] = {0.f, 0.f, 0.f, 0.f}; // kappa state (items with j>=20)

#define GSTEP(ks) { \
    const int uu_ = (ks) * 4 + g4; \
    const short8 bh = LDFRAG(shi, bb, uu_); \
    const short8 bl = LDFRAG(slo, bb, uu_); \
    const short8 ah0 = LDFRAG(whi, r16, uu_); \
    const short8 al0 = LDFRAG(wlo, r16, uu_); \
    const short8 ah1 = LDFRAG(whi, 16 + r16, uu_); \
    const short8 al1 = LDFRAG(wlo, 16 + r16, uu_); \
    a0 = __builtin_amdgcn_mfma_f32_16x16x32_bf16(ah0, bh, a0, 0, 0, 0); \
    a0 = __builtin_amdgcn_mfma_f32_16x16x32_bf16(ah0, bl, a0, 0, 0, 0); \
    a0 = __builtin_amdgcn_mfma_f32_16x16x32_bf16(al0, bh, a0, 0, 0, 0); \
    a1 = __builtin_amdgcn_mfma_f32_16x16x32_bf16(ah1, bh, a1, 0, 0, 0); \
    a1 = __builtin_amdgcn_mfma_f32_16x16x32_bf16(ah1, bl, a1, 0, 0, 0); \
    a1 = __builtin_amdgcn_mfma_f32_16x16x32_bf16(al1, bh, a1, 0, 0, 0); \
  }

  for (int t = 0; t <= T_; ++t) {
    if (t == T_ && !isWriter) break;           // non-writers fully done

    const unsigned* pIn  = gbuf + (size_t)((t & 1) ^ 1) * (B_ * HB);
    unsigned*       pOut = gbuf + (size_t)(t & 1) * (B_ * HB);

    // ---- P1: single sync point — all h(t-1) + p-partials landed ----
    if (t > 0 && tid < 4) {
      unsigned* line = c1l + tid * 32;
      const unsigned tgt = 16u * (unsigned)t;
      while (flag_ld(line) < tgt) __builtin_amdgcn_s_sleep(1);
      acq_fence(line);
    }
    __syncthreads();

    // ---- P2: stage h(t-1) into LDS (split bf16, swizzled); zero window cols; x prefetch ----
    float xv0 = 0.f, xv1 = 0.f, xv2 = 0.f;
    {
      const int sb = tid & 31, seg = tid >> 5;
      const unsigned* grow = pIn + (size_t)(b0 + sb) * HB + seg * 64;
      uint4 v[16];
      #pragma unroll
      for (int i = 0; i < 16; ++i) v[i] = *(const uint4*)(grow + i * 4);
      #pragma unroll
      for (int i = 0; i < 16; ++i) {
        const int k = seg * 64 + i * 4;
        const int idx = SWIDX(sb, k);
        const unsigned h01 = (v[i].x >> 16) | ((v[i].y >> 16) << 16);
        const unsigned h23 = (v[i].z >> 16) | ((v[i].w >> 16) << 16);
        const unsigned l01 = (v[i].x & 0xffffu) | ((v[i].y & 0xffffu) << 16);
        const unsigned l23 = (v[i].z & 0xffffu) | ((v[i].w & 0xffffu) << 16);
        *(uint2*)&shi[idx] = make_uint2(h01, h23);
        *(uint2*)&slo[idx] = make_uint2(l01, l23);
      }
      #pragma unroll
      for (int i = 0; i < 10; ++i) {           // zero window cols (scatter accumulates)
        const int c = seg * 10 + i;
        const int idx = SWIDX(sb, H_ + c);
        shi[idx] = 0; slo[idx] = 0;
      }
      if (kh == 0 && t < T_) {
        const float* xp = x + ((size_t)(b0 + bb) * T_ + t) * IN_;
        xv0 = xp[0]; xv1 = xp[1]; xv2 = xp[2];
      }
    }
    __syncthreads();

    // ---- P3: window(t-1) from EXACT integer-summed p (redundant per block) ----
    if (t >= 1) {
      #pragma unroll
      for (int r = 0; r < 4; ++r) {
        const int item = tid + 256 * r;
        if (item < 960) {
          const int b = item / 30, j = item - b * 30;
          const long long v = pacc_g[b * 30 + j];
          const int hi = (int)(v >> 32);
          const unsigned lo = (unsigned)(v & 0xffffffffLL);
          const float pv = (float)hi + (float)lo * 0x1p-32f + b_win[j];
          float ev = __expf(pv);
          if (j >= 20) { ev += kprevf[r]; kprevf[r] = ev; }  // kappa (register state)
          pbufS[b][j] = ev;
        }
      }
      __syncthreads();

      // phi per (pb, ug): 8 u-values in registers
      float al[10], be[10], ka[10];
      #pragma unroll
      for (int k2 = 0; k2 < 10; ++k2) {
        al[k2] = pbufS[pb][k2];
        be[k2] = pbufS[pb][10 + k2];
        ka[k2] = pbufS[pb][20 + k2];
      }
      float ph[8];
      #pragma unroll
      for (int i = 0; i < 8; ++i) {
        const float fu = (float)(ug * 8 + i);
        float s = 0.0f;
        #pragma unroll
        for (int k2 = 0; k2 < 10; ++k2) {
          const float d = ka[k2] - fu;
          s = fmaf(al[k2], __expf(-be[k2] * d * d), s);
        }
        ph[i] = s;
      }
      if (isWriter && pb == ub) {              // raw phi out (batch ub only)
        #pragma unroll
        for (int i = 0; i < 8; ++i)
          out[OFF_PHI + ((size_t)wb_b * T_ + (t - 1)) * U_ + ug * 8 + i] = ph[i];
      }
      #pragma unroll
      for (int i = 0; i < 8; ++i) ph[i] *= msk[i];

      // scatter into state LDS window cols (split hi/lo). In-wave rounds over ug
      // serialize writers of the same row; DS ops of a wave execute in order.
      #pragma unroll
      for (int r = 0; r < 8; ++r) {
        if (ug == r) {
          #pragma unroll
          for (int i = 0; i < 8; ++i) {
            const int idx = SWIDX(pb, H_ + snt[i]);
            float cur = comb_hl(shi[idx], slo[idx]) + ph[i];
            const unsigned pk = pack_hl(cur);
            shi[idx] = (short)(pk >> 16);
            slo[idx] = (short)(pk & 0xffffu);
          }
        }
        asm volatile("" ::: "memory");
      }
      __syncthreads();
      if (isWriter && tid < C_) {              // window out (batch ub)
        const int idx = SWIDX(ub, H_ + tid);
        out[OFF_W + ((size_t)wb_b * T_ + (t - 1)) * C_ + tid] = comb_hl(shi[idx], slo[idx]);
      }
    }
    if (t == T_) break;                        // writer epilogue done

    // ---- P4: full gate GEMM, k 0..607 ----
    f32x4 a0 = {0.f, 0.f, 0.f, 0.f}, a1 = {0.f, 0.f, 0.f, 0.f};
    if (kh == 0) {
      #pragma unroll
      for (int ks = 0; ks < 8; ++ks) GSTEP(ks);
      GSTEP(16);
    } else {
      #pragma unroll
      for (int ks = 8; ks < 16; ++ks) GSTEP(ks);
      GSTEP(17); GSTEP(18);
    }

    // ---- P5: cross-kh reduce, LSTM pointwise, publish h ----
    __syncthreads();
    if (kh == 1) {
      #pragma unroll
      for (int e = 0; e < 4; ++e) {
        pbf[(ni * 2 + 0) * 256 + (g4 * 4 + e) * 16 + r16] = a0[e];
        pbf[(ni * 2 + 1) * 256 + (g4 * 4 + e) * 16 + r16] = a1[e];
      }
    }
    __syncthreads();
    if (kh == 0) {
      #pragma unroll
      for (int mi = 0; mi < 2; ++mi) {
        float ge[4];
        #pragma unroll
        for (int e = 0; e < 4; ++e) {
          const int r = mi * 16 + g4 * 4 + e;
          const float av = ((mi == 0) ? a0[e] : a1[e]) + pbf[(ni * 2 + mi) * 256 + (g4 * 4 + e) * 16 + r16];
          ge[e] = av + xwb[r*4+0]*xv0 + xwb[r*4+1]*xv1 + xwb[r*4+2]*xv2 + xwb[r*4+3];
        }
        const float iv = sigmoidf_(ge[0]);
        const float fv = sigmoidf_(ge[1]);
        const float gv = tanhf(ge[2]);
        const float ov = sigmoidf_(ge[3]);
        const float cprev = (mi == 0) ? cr0 : cr1;
        const float cv = fmaf(fv, cprev, iv * gv);
        if (mi == 0) cr0 = cv; else cr1 = cv;
        const float hv = ov * tanhf(cv);
        const int uu = mi * 4 + g4;
        hT[uu * 32 + bb] = hv;                 // exact f32 h for p-partials
        stb_u32(&pOut[(size_t)(b0 + bb) * HB + (u0 + uu)], pack_hl(hv));
        out[OFF_H + ((size_t)(b0 + bb) * T_ + t) * H_ + (u0 + uu)] = hv;
      }
    }
    __syncthreads();                           // hT visible

    // ---- P9: f32 p-partials -> fixed-point delta atomicAdd (deterministic sum) ----
    #pragma unroll
    for (int r = 0; r < 4; ++r) {
      const int item = tid + 256 * r;
      if (item < 960) {
        const int b = item / 30, j = item - b * 30;
        float s = 0.0f;
        #pragma unroll
        for (int uu = 0; uu < 8; ++uu) s = fmaf(wwin[uu * 30 + j], hT[uu * 32 + b], s);
        const long long nv = llrintf(s * 4294967296.0f);   // exact: *2^32 is exponent shift
        const unsigned long long d = (unsigned long long)(nv - prevp[r]);
        prevp[r] = nv;
        __hip_atomic_fetch_add((unsigned long long*)(pacc_g + b * 30 + j), d,
                               __ATOMIC_RELAXED, __HIP_MEMORY_SCOPE_AGENT);
      }
    }
    fence_vm();                                // h stores + atomics at coherence point
    __syncthreads();
    if (tid == 0) flag_add(c1l + (ub & 3) * 32);
  }
#undef GSTEP
}

extern "C" void kernel_launch(void* const* d_in, const int* in_sizes, int n_in,
                              void* d_out, int out_size, void* d_ws, size_t ws_size,
                              hipStream_t stream) {
  const float* x     = (const float*)d_in[0];
  const int*   sent  = (const int*)  d_in[1];
  const float* smask = (const float*)d_in[2];
  const float* W_ih  = (const float*)d_in[3];
  const float* W_hh  = (const float*)d_in[4];
  const float* b_ih  = (const float*)d_in[5];
  const float* b_hh  = (const float*)d_in[6];
  const float* W_win = (const float*)d_in[7];
  const float* b_win = (const float*)d_in[8];
  float* ws  = (float*)d_ws;
  float* out = (float*)d_out;

  hipLaunchKernelGGL(init_ws_kernel, dim3(512), dim3(256), 0, stream, ws);
  hipLaunchKernelGGL(graves_kernel, dim3(NG * BPG), dim3(NT), 0, stream,
                     x, sent, smask, W_ih, W_hh, b_ih, b_hh, W_win, b_win, out, ws);
}